// Round 12
// baseline (451.652 us; speedup 1.0000x reference)
//
#include <hip/hip_runtime.h>
#include <cstdio>
#include <cstdint>

#define N_TOK 16384
#define DIM   1024
#define NEXP  8
#define HID   2048
#define BK    32

typedef __attribute__((ext_vector_type(8))) short bf16x8;
typedef __attribute__((ext_vector_type(4))) float f32x4;

__device__ inline ushort f2bf(float f) {
  uint32_t u = __float_as_uint(f);
  uint32_t r = (u + 0x7fffu + ((u >> 16) & 1u)) >> 16;
  return (ushort)r;
}
__device__ inline float bf2f(ushort u) { return __uint_as_float(((uint32_t)u) << 16); }

// async global->LDS, 16B per lane; LDS dest is wave-uniform base + lane*16
__device__ __forceinline__ void gload_lds16(const void* g, void* l) {
  __builtin_amdgcn_global_load_lds((const __attribute__((address_space(1))) void*)g,
                                   (__attribute__((address_space(3))) void*)l, 16, 0, 0);
}

#define WAITV(N) asm volatile("s_waitcnt vmcnt(" #N ")" ::: "memory")
#define PBAR()  do { __builtin_amdgcn_s_barrier(); __builtin_amdgcn_sched_barrier(0); } while (0)

// ---------------- router: fp32 logits, top-2; per-block histogram; fused x->bf16 ----------
__global__ __launch_bounds__(256) void router_kernel(
    const float* __restrict__ x, const float* __restrict__ rw,
    const float* __restrict__ rb, int* __restrict__ blkcnt,
    int* __restrict__ tok_e, float* __restrict__ tok_g,
    ushort* __restrict__ xb) {
  __shared__ float wT[NEXP][DIM];
  __shared__ int hist[NEXP];
  if (threadIdx.x < NEXP) hist[threadIdx.x] = 0;
  for (int i = threadIdx.x; i < NEXP * DIM; i += 256) {
    int d = i >> 3, e = i & 7;
    wT[e][d] = rw[i];
  }
  __syncthreads();
  int wave = threadIdx.x >> 6, lane = threadIdx.x & 63;
  int t0 = blockIdx.x * 16 + wave * 4;
#pragma unroll
  for (int it = 0; it < 4; ++it) {
    int t = t0 + it;
    const float* xr = x + (size_t)t * DIM;
    float acc[NEXP];
#pragma unroll
    for (int e = 0; e < NEXP; ++e) acc[e] = 0.f;
#pragma unroll
    for (int j = 0; j < DIM / 64; ++j) {
      int d = lane + j * 64;
      float xv = xr[d];
#pragma unroll
      for (int e = 0; e < NEXP; ++e) acc[e] += xv * wT[e][d];
    }
    float lg[NEXP];
#pragma unroll
    for (int e = 0; e < NEXP; ++e) {
      float v = acc[e];
      for (int o = 32; o > 0; o >>= 1) v += __shfl_xor(v, o);
      lg[e] = v + rb[e];
    }
    int i0 = 0; float m0 = lg[0];
#pragma unroll
    for (int e = 1; e < NEXP; ++e) if (lg[e] > m0) { m0 = lg[e]; i0 = e; }
    int i1 = -1; float m1 = -3.4e38f;
#pragma unroll
    for (int e = 0; e < NEXP; ++e) if (e != i0 && lg[e] > m1) { m1 = lg[e]; i1 = e; }
    float g0 = 1.f / (1.f + expf(m1 - m0));
    float g1 = 1.f - g0;
    if (lane == 0) {
      tok_e[2 * t] = i0; tok_e[2 * t + 1] = i1;
      tok_g[2 * t] = g0; tok_g[2 * t + 1] = g1;
      atomicAdd(&hist[i0], 1); atomicAdd(&hist[i1], 1);  // LDS atomics
    }
  }
  // fused x -> bf16 for this block's 16 rows (L1/L2-hot)
  {
    const float* xs = x + (size_t)blockIdx.x * 16 * DIM;
    ushort* xd = xb + (size_t)blockIdx.x * 16 * DIM;
    for (int i = threadIdx.x; i < 16 * DIM / 4; i += 256) {
      float4 v = *(const float4*)(xs + i * 4);
      ushort4 u = { f2bf(v.x), f2bf(v.y), f2bf(v.z), f2bf(v.w) };
      *(ushort4*)(xd + i * 4) = u;
    }
  }
  __syncthreads();
  if (threadIdx.x < NEXP) blkcnt[blockIdx.x * NEXP + threadIdx.x] = hist[threadIdx.x];
}

// ---------------- scan: blkcnt[1024][8] -> offs[9], blkbase[1024][8] (parallel) ----------
__global__ __launch_bounds__(512) void scan_kernel(const int* __restrict__ blkcnt,
                                                   int* __restrict__ blkbase,
                                                   int* __restrict__ offs) {
  __shared__ int s[64][8];
  __shared__ int chunkoff[64][8];
  __shared__ int offsh[8];
  int tid = threadIdx.x;
  int e = tid & 7, chunk = tid >> 3;   // 64 chunks x 16 blocks
  int b0 = chunk * 16;
  int csum = 0;
#pragma unroll
  for (int b = 0; b < 16; ++b) csum += blkcnt[(b0 + b) * 8 + e];
  s[chunk][e] = csum;
  __syncthreads();
  int wave = tid >> 6, lane = tid & 63;
  int v = s[lane][wave];
  for (int o = 1; o < 64; o <<= 1) {
    int u = __shfl_up(v, o);
    if (lane >= o) v += u;
  }
  if (lane == 63) offsh[wave] = v;
  chunkoff[lane][wave] = v - s[lane][wave];
  __syncthreads();
  if (tid < 9) {
    int oe = 0;
    for (int j = 0; j < tid && j < 8; ++j) oe += offsh[j];
    offs[tid] = oe;
  }
  int oe2 = 0;
#pragma unroll
  for (int j = 0; j < 8; ++j) oe2 += (j < e) ? offsh[j] : 0;
  int base = oe2 + chunkoff[chunk][e];
  for (int b = 0; b < 16; ++b) {
    int idx = (b0 + b) * 8 + e;
    int c = blkcnt[idx];
    blkbase[idx] = base;
    base += c;
  }
}

// ---------------- gather: slot lists; slot_token packs token | k<<16 ----------------
__global__ __launch_bounds__(64) void gather_kernel(
    const int* __restrict__ tok_e, const float* __restrict__ tok_g,
    const int* __restrict__ blkbase, int* __restrict__ slot_token,
    float* __restrict__ slot_gate) {
  __shared__ int lcnt[NEXP];
  int tid = threadIdx.x, blk = blockIdx.x;   // 1024 blocks x 16 tokens
  if (tid < NEXP) lcnt[tid] = blkbase[blk * NEXP + tid];
  __syncthreads();
  if (tid < 32) {
    int t = blk * 16 + (tid >> 1);
    int k = tid & 1;
    int e = tok_e[2 * t + k];
    int s = atomicAdd(&lcnt[e], 1);   // LDS atomic
    slot_token[s] = t | (k << 16);
    slot_gate[s] = tok_g[2 * t + k];
  }
}

// ---------------- transpose + f32->bf16 convert (vectorized: float4 loads, 16B stores) ----
// src: [E][R][C] f32  ->  dst: [E][C][R] bf16
template <int R, int C>
__global__ __launch_bounds__(256) void transpose_cvt(const float* __restrict__ src,
                                                     ushort* __restrict__ dst) {
  __shared__ float tile[64][65];
  int e = blockIdx.z;
  const float* s = src + (size_t)e * R * C;
  ushort* d = dst + (size_t)e * R * C;
  int r0 = blockIdx.y * 64, c0 = blockIdx.x * 64;
  int tid = threadIdx.x;
#pragma unroll
  for (int i = 0; i < 4; ++i) {
    int idx = i * 256 + tid;            // 0..1023 -> 64 rows x 16 float4
    int r = idx >> 4, c4 = (idx & 15) * 4;
    float4 v = *(const float4*)(s + (size_t)(r0 + r) * C + c0 + c4);
    tile[r][c4] = v.x; tile[r][c4 + 1] = v.y; tile[r][c4 + 2] = v.z; tile[r][c4 + 3] = v.w;
  }
  __syncthreads();
#pragma unroll
  for (int i = 0; i < 2; ++i) {
    int idx = i * 256 + tid;            // 0..511 -> 64 out-rows x 8 groups of 8
    int orow = idx >> 3, g = (idx & 7) * 8;
    uint32_t p0 = (uint32_t)f2bf(tile[g + 0][orow]) | ((uint32_t)f2bf(tile[g + 1][orow]) << 16);
    uint32_t p1 = (uint32_t)f2bf(tile[g + 2][orow]) | ((uint32_t)f2bf(tile[g + 3][orow]) << 16);
    uint32_t p2 = (uint32_t)f2bf(tile[g + 4][orow]) | ((uint32_t)f2bf(tile[g + 5][orow]) << 16);
    uint32_t p3 = (uint32_t)f2bf(tile[g + 6][orow]) | ((uint32_t)f2bf(tile[g + 7][orow]) << 16);
    int4 v = { (int)p0, (int)p1, (int)p2, (int)p3 };
    *(int4*)(d + (size_t)(c0 + orow) * R + r0 + g) = v;
  }
}

// ====== 256x256 grouped GEMM, 8 waves, BK=32, 4-buf depth-3 counted-vmcnt + T5 setprio =====
// round-11 core verbatim + s_setprio(1) around each MFMA cluster.

// gemm1: h = relu(x_gather @ w1T^T + b1)   K=1024 -> T=32 subtiles
__global__ __launch_bounds__(512, 1) void gemm1_kernel(
    const ushort* __restrict__ xb, const ushort* __restrict__ w1T,
    const float* __restrict__ b1, const int* __restrict__ offs,
    const int* __restrict__ slot_token, ushort* __restrict__ h) {
  int flat = blockIdx.x;                     // nwg = 8*64*8 = 4096
  int swz = (flat & 7) * 512 + (flat >> 3);  // XCD x -> expert x
  int e = swz >> 9;
  int rem = swz & 511;
  int mt = rem >> 3;
  int nt = rem & 7;
  int off = offs[e];
  int cn = offs[e + 1] - off;
  if (mt * 256 >= cn) return;

  __shared__ __align__(16) ushort AB[4 * 16384];  // 128 KB
  __shared__ int toks[256];
  int tid = threadIdx.x;
  if (tid < 256) {
    int r = mt * 256 + tid;
    toks[tid] = slot_token[off + (r < cn ? r : 0)] & 0xffff;
  }
  __syncthreads();
  int wave = tid >> 6, lane = tid & 63;
  int wm = (wave >> 2) * 128, wn = (wave & 3) * 64;

  const ushort* Bsrc = w1T + (size_t)e * HID * DIM + (size_t)(nt * 256) * DIM;
  int colsw = ((lane & 3) ^ ((lane >> 3) & 3)) * 8;  // pre-swizzled source col (elems)
  int r0 = wave * 16 + (lane >> 2);
  const ushort* ag0 = xb + (size_t)toks[r0] * DIM + colsw;
  const ushort* ag1 = xb + (size_t)toks[128 + r0] * DIM + colsw;
  const ushort* bg0 = Bsrc + (size_t)r0 * DIM + colsw;
  const ushort* bg1 = Bsrc + (size_t)(128 + r0) * DIM + colsw;
  int ldsA0 = (wave * 16) * BK;
  int ldsA1 = (128 + wave * 16) * BK;
  int ldsB0 = 8192 + ldsA0;
  int ldsB1 = 8192 + ldsA1;

  f32x4 acc[8][4];
#pragma unroll
  for (int i = 0; i < 8; ++i)
#pragma unroll
    for (int j = 0; j < 4; ++j) acc[i][j] = (f32x4){0.f, 0.f, 0.f, 0.f};

  int rdo = (lane & 15) * 64 + ((((lane >> 4) & 3) << 4) ^ ((((lane & 15) >> 1) & 3) << 4));

  auto stage = [&](int buf) {
    ushort* lb = &AB[buf * 16384];
    gload_lds16(ag0, lb + ldsA0); ag0 += BK;
    gload_lds16(ag1, lb + ldsA1); ag1 += BK;
    gload_lds16(bg0, lb + ldsB0); bg0 += BK;
    gload_lds16(bg1, lb + ldsB1); bg1 += BK;
  };
  auto compute = [&](int buf) {
    const char* base = (const char*)AB + (size_t)buf * 32768;
    bf16x8 a[8], b[4];
#pragma unroll
    for (int mi = 0; mi < 8; ++mi)
      a[mi] = *(const bf16x8*)(base + (wm + mi * 16) * 64 + rdo);
#pragma unroll
    for (int ni = 0; ni < 4; ++ni)
      b[ni] = *(const bf16x8*)(base + 16384 + (wn + ni * 16) * 64 + rdo);
    __builtin_amdgcn_s_setprio(1);
#pragma unroll
    for (int mi = 0; mi < 8; ++mi)
#pragma unroll
      for (int ni = 0; ni < 4; ++ni)
        acc[mi][ni] = __builtin_amdgcn_mfma_f32_16x16x32_bf16(a[mi], b[ni], acc[mi][ni], 0, 0, 0);
    __builtin_amdgcn_s_setprio(0);
  };

  const int T = DIM / BK;  // 32
  stage(0); stage(1); stage(2);
  for (int t4 = 0; t4 < T - 4; t4 += 4) {
    WAITV(8); PBAR(); stage(3); compute(0);
    WAITV(8); PBAR(); stage(0); compute(1);
    WAITV(8); PBAR(); stage(1); compute(2);
    WAITV(8); PBAR(); stage(2); compute(3);
  }
  WAITV(8); PBAR(); stage(3); compute(0);
  WAITV(8); PBAR(); compute(1);
  WAITV(4); PBAR(); compute(2);
  WAITV(0); PBAR(); compute(3);

  // ---- epilogue: bias+relu -> bf16 -> swizzled LDS C[256][512B] (aliases AB) ----
  __syncthreads();
  char* Cb = (char*)AB;
  int ln = lane & 15, lg4 = (lane >> 4) * 4;
#pragma unroll
  for (int ni = 0; ni < 4; ++ni) {
    int coll = wn + ni * 16 + ln;               // local col 0..255
    float bias = b1[(size_t)e * HID + nt * 256 + coll];
#pragma unroll
    for (int mi = 0; mi < 8; ++mi) {
#pragma unroll
      for (int rg = 0; rg < 4; ++rg) {
        int row = wm + mi * 16 + lg4 + rg;      // local row 0..255
        float v = fmaxf(acc[mi][ni][rg] + bias, 0.f);
        int slot = (coll >> 3) ^ (row & 7);
        *(ushort*)(Cb + row * 512 + slot * 16 + (coll & 7) * 2) = f2bf(v);
      }
    }
  }
  __syncthreads();
#pragma unroll
  for (int rr = 0; rr < 16; ++rr) {
    int row = rr * 16 + (tid >> 5);
    int scol = tid & 31;
    int4 v = *(const int4*)(Cb + row * 512 + ((scol ^ (row & 7)) << 4));
    int r = mt * 256 + row;
    if (r < cn)
      *(int4*)(h + (size_t)(off + r) * HID + nt * 256 + scol * 8) = v;
  }
}

// gemm2: y[2t+k] = gate * (h @ w2T^T + b2)  (bf16, non-atomic scatter; y aliases d_out)
__global__ __launch_bounds__(512, 1) void gemm2_kernel(
    const ushort* __restrict__ h, const ushort* __restrict__ w2T,
    const float* __restrict__ b2, const int* __restrict__ offs,
    const int* __restrict__ slot_token, const float* __restrict__ slot_gate,
    ushort* __restrict__ y) {
  int flat = blockIdx.x;                     // nwg = 4*64*8 = 2048
  int swz = (flat & 7) * 256 + (flat >> 3);  // XCD x -> expert x
  int e = swz >> 8;
  int rem = swz & 255;
  int mt = rem >> 2;
  int nt = rem & 3;
  int off = offs[e];
  int cn = offs[e + 1] - off;
  if (mt * 256 >= cn) return;

  __shared__ __align__(16) ushort AB[4 * 16384];  // 128 KB
  __shared__ int yrows[256];
  __shared__ float gts[256];
  int tid = threadIdx.x;
  if (tid < 256) {
    int r = mt * 256 + tid;
    int s = off + (r < cn ? r : 0);
    int tk = slot_token[s];
    yrows[tid] = ((tk & 0xffff) << 1) | (tk >> 16);
    gts[tid] = slot_gate[s];
  }
  __syncthreads();
  int wave = tid >> 6, lane = tid & 63;
  int wm = (wave >> 2) * 128, wn = (wave & 3) * 64;

  const ushort* Bsrc = w2T + (size_t)e * DIM * HID + (size_t)(nt * 256) * HID;
  int colsw = ((lane & 3) ^ ((lane >> 3) & 3)) * 8;
  int r0 = wave * 16 + (lane >> 2);
  int ra0 = mt * 256 + r0;       ra0 = ra0 < cn ? ra0 : 0;
  int ra1 = mt * 256 + 128 + r0; ra1 = ra1 < cn ? ra1 : 0;
  const ushort* ag0 = h + (size_t)(off + ra0) * HID + colsw;
  const ushort* ag1 = h + (size_t)(off + ra1) * HID + colsw;
  const ushort* bg0 = Bsrc + (size_t)r0 * HID + colsw;
  const ushort* bg1 = Bsrc + (size_t)(128 + r0) * HID + colsw;
  int ldsA0 = (wave * 16) * BK;
  int ldsA1 = (128 + wave * 16) * BK;
  int ldsB0 = 8192 + ldsA0;
  int ldsB1 = 8192 + ldsA1;

  f32x4 acc[8][4];
#pragma unroll
  for (int i = 0; i < 8; ++i)
#pragma unroll
    for (int j = 0; j < 4; ++j) acc[i][j] = (f32x4){0.f, 0.f, 0.f, 0.f};

  int rdo = (lane & 15) * 64 + ((((lane >> 4) & 3) << 4) ^ ((((lane & 15) >> 1) & 3) << 4));

  auto stage = [&](int buf) {
    ushort* lb = &AB[buf * 16384];
    gload_lds16(ag0, lb + ldsA0); ag0 += BK;
    gload_lds16(ag1, lb + ldsA1); ag1 += BK;
    gload_lds16(bg0, lb + ldsB0); bg0 += BK;
    gload_lds16(bg1, lb + ldsB1); bg1 += BK;
  };
  auto compute = [&](int buf) {
    const char* base = (const char*)AB + (size_t)buf * 32768;
    bf16x8 a[8], b[4];
#pragma unroll
    for (int mi = 0; mi < 8; ++mi)
      a[mi] = *(const bf16x8*)(base + (wm + mi * 16) * 64 + rdo);
#pragma unroll
    for (int ni = 0; ni < 4; ++ni)
      b[ni] = *(const bf16x8*)(base + 16384 + (wn + ni * 16) * 64 + rdo);
    __builtin_amdgcn_s_setprio(1);
#pragma unroll
    for (int mi = 0; mi < 8; ++mi)
#pragma unroll
      for (int ni = 0; ni < 4; ++ni)
        acc[mi][ni] = __builtin_amdgcn_mfma_f32_16x16x32_bf16(a[mi], b[ni], acc[mi][ni], 0, 0, 0);
    __builtin_amdgcn_s_setprio(0);
  };

  const int T = HID / BK;  // 64
  stage(0); stage(1); stage(2);
  for (int t4 = 0; t4 < T - 4; t4 += 4) {
    WAITV(8); PBAR(); stage(3); compute(0);
    WAITV(8); PBAR(); stage(0); compute(1);
    WAITV(8); PBAR(); stage(1); compute(2);
    WAITV(8); PBAR(); stage(2); compute(3);
  }
  WAITV(8); PBAR(); stage(3); compute(0);
  WAITV(8); PBAR(); compute(1);
  WAITV(4); PBAR(); compute(2);
  WAITV(0); PBAR(); compute(3);

  // ---- epilogue: gate*(acc+bias) -> bf16 -> swizzled LDS C (aliases AB) -> 16B stores ----
  __syncthreads();
  char* Cb = (char*)AB;
  int ln = lane & 15, lg4 = (lane >> 4) * 4;
#pragma unroll
  for (int ni = 0; ni < 4; ++ni) {
    int coll = wn + ni * 16 + ln;
    float bias = b2[(size_t)e * DIM + nt * 256 + coll];
#pragma unroll
    for (int mi = 0; mi < 8; ++mi) {
#pragma unroll
      for (int rg = 0; rg < 4; ++rg) {
        int row = wm + mi * 16 + lg4 + rg;
        float v = gts[row] * (acc[mi][ni][rg] + bias);
        int slot = (coll >> 3) ^ (row & 7);
        *(ushort*)(Cb + row * 512 + slot * 16 + (coll & 7) * 2) = f2bf(v);
      }
    }
  }
  __syncthreads();
#pragma unroll
  for (int rr = 0; rr < 16; ++rr) {
    int row = rr * 16 + (tid >> 5);
    int scol = tid & 31;
    int4 v = *(const int4*)(Cb + row * 512 + ((scol ^ (row & 7)) << 4));
    int r = mt * 256 + row;
    if (r < cn)
      *(int4*)(y + (size_t)yrows[row] * DIM + nt * 256 + scol * 8) = v;
  }
}

// ---------------- combine: out[t] = y[2t] + y[2t+1] (in-place, y aliases out) ------------
__global__ __launch_bounds__(256) void combine_kernel(float* __restrict__ out) {
  int t = blockIdx.x;
  int d = threadIdx.x;  // 4 outputs each
  const ushort* y = (const ushort*)out;
  ushort4 a = *(const ushort4*)(y + (size_t)(2 * t) * DIM + 4 * d);
  ushort4 b = *(const ushort4*)(y + (size_t)(2 * t + 1) * DIM + 4 * d);
  float4 r;
  r.x = bf2f(a.x) + bf2f(b.x);
  r.y = bf2f(a.y) + bf2f(b.y);
  r.z = bf2f(a.z) + bf2f(b.z);
  r.w = bf2f(a.w) + bf2f(b.w);
  __syncthreads();  // all loads of this block's 4KB before any store over it
  *(float4*)(out + (size_t)t * DIM + 4 * d) = r;
}

extern "C" void kernel_launch(void* const* d_in, const int* in_sizes, int n_in,
                              void* d_out, int out_size, void* d_ws, size_t ws_size,
                              hipStream_t stream) {
  const float* x  = (const float*)d_in[0];
  const float* rw = (const float*)d_in[1];
  const float* rb = (const float*)d_in[2];
  const float* w1 = (const float*)d_in[3];
  const float* b1 = (const float*)d_in[4];
  const float* w2 = (const float*)d_in[5];
  const float* b2 = (const float*)d_in[6];
  float* out = (float*)d_out;
  char* ws = (char*)d_ws;

  const size_t o_ctrl = 0;                    // offs[9] (+pad)
  const size_t o_toke = 256;
  const size_t o_tokg = o_toke + 131072;
  const size_t o_stok = o_tokg + 131072;
  const size_t o_sgat = o_stok + 131072;
  const size_t o_xb   = o_sgat + 131072;
  const size_t o_w1T  = o_xb + (size_t)N_TOK * DIM * 2;
  const size_t o_h    = o_w1T + (size_t)NEXP * HID * DIM * 2;
  const size_t required = o_h + (size_t)N_TOK * 2 * HID * 2;  // ~202 MB
  if (ws_size < required) {
    fprintf(stderr, "kernel_launch: ws too small: have %zu need %zu\n", ws_size, required);
    return;
  }
  int* offs       = (int*)(ws + o_ctrl);
  int* tok_e      = (int*)(ws + o_toke);
  float* tok_g    = (float*)(ws + o_tokg);
  int* slot_token = (int*)(ws + o_stok);
  float* slot_gate= (float*)(ws + o_sgat);
  ushort* xb      = (ushort*)(ws + o_xb);
  ushort* w2T     = (ushort*)(ws + o_xb);   // aliased with xb (xb dead after gemm1)
  ushort* w1T     = (ushort*)(ws + o_w1T);
  ushort* hbuf    = (ushort*)(ws + o_h);
  int* blkcnt     = (int*)(ws + o_h);       // aliases hbuf (pre-gemm1 only)
  int* blkbase    = blkcnt + 1024 * NEXP;

  // no memsets needed: router/scan/gather write all control words; gemm2's slot map is a
  // bijection onto all y rows and nt covers all columns, so every d_out byte is written.

  // router (+fused x->bf16) -> scan -> gather
  router_kernel<<<N_TOK / 16, 256, 0, stream>>>(x, rw, rb, blkcnt, tok_e, tok_g, xb);
  scan_kernel<<<1, 512, 0, stream>>>(blkcnt, blkbase, offs);
  gather_kernel<<<N_TOK / 16, 64, 0, stream>>>(tok_e, tok_g, blkbase, slot_token, slot_gate);

  // w1 [E][D][H] -> w1T [E][H][D]
  transpose_cvt<DIM, HID><<<dim3(HID / 64, DIM / 64, NEXP), 256, 0, stream>>>(w1, w1T);

  gemm1_kernel<<<8 * 64 * NEXP, 512, 0, stream>>>(xb, w1T, b1, offs, slot_token, hbuf);

  // xb dead; build w2T in its place: w2 [E][H][D] -> w2T [E][D][H]
  transpose_cvt<HID, DIM><<<dim3(DIM / 64, HID / 64, NEXP), 256, 0, stream>>>(w2, w2T);

  // gemm2 scatters gated bf16 rows into y (aliases d_out), then combine in-place
  gemm2_kernel<<<4 * 64 * NEXP, 512, 0, stream>>>(hbuf, w2T, b2, offs, slot_token, slot_gate,
                                                  (ushort*)d_out);
  combine_kernel<<<N_TOK, 256, 0, stream>>>(out);
}

// Round 13
// 429.511 us; speedup vs baseline: 1.0516x; 1.0516x over previous
//
#include <hip/hip_runtime.h>
#include <cstdio>
#include <cstdint>

#define N_TOK 16384
#define DIM   1024
#define NEXP  8
#define HID   2048
#define BK    32

typedef __attribute__((ext_vector_type(8))) short bf16x8;
typedef __attribute__((ext_vector_type(4))) float f32x4;

__device__ inline ushort f2bf(float f) {
  uint32_t u = __float_as_uint(f);
  uint32_t r = (u + 0x7fffu + ((u >> 16) & 1u)) >> 16;
  return (ushort)r;
}
__device__ inline float bf2f(ushort u) { return __uint_as_float(((uint32_t)u) << 16); }

// async global->LDS, 16B per lane; LDS dest is wave-uniform base + lane*16
__device__ __forceinline__ void gload_lds16(const void* g, void* l) {
  __builtin_amdgcn_global_load_lds((const __attribute__((address_space(1))) void*)g,
                                   (__attribute__((address_space(3))) void*)l, 16, 0, 0);
}

#define WAITV(N) asm volatile("s_waitcnt vmcnt(" #N ")" ::: "memory")
#define PBAR()  do { __builtin_amdgcn_s_barrier(); __builtin_amdgcn_sched_barrier(0); } while (0)

// ---------------- router: fp32 logits, top-2; per-block histogram; fused x->bf16 ----------
__global__ __launch_bounds__(256) void router_kernel(
    const float* __restrict__ x, const float* __restrict__ rw,
    const float* __restrict__ rb, int* __restrict__ blkcnt,
    int* __restrict__ tok_e, float* __restrict__ tok_g,
    ushort* __restrict__ xb) {
  __shared__ float wT[NEXP][DIM];
  __shared__ int hist[NEXP];
  if (threadIdx.x < NEXP) hist[threadIdx.x] = 0;
  for (int i = threadIdx.x; i < NEXP * DIM; i += 256) {
    int d = i >> 3, e = i & 7;
    wT[e][d] = rw[i];
  }
  __syncthreads();
  int wave = threadIdx.x >> 6, lane = threadIdx.x & 63;
  int t0 = blockIdx.x * 16 + wave * 4;
#pragma unroll
  for (int it = 0; it < 4; ++it) {
    int t = t0 + it;
    const float* xr = x + (size_t)t * DIM;
    float acc[NEXP];
#pragma unroll
    for (int e = 0; e < NEXP; ++e) acc[e] = 0.f;
#pragma unroll
    for (int j = 0; j < DIM / 64; ++j) {
      int d = lane + j * 64;
      float xv = xr[d];
#pragma unroll
      for (int e = 0; e < NEXP; ++e) acc[e] += xv * wT[e][d];
    }
    float lg[NEXP];
#pragma unroll
    for (int e = 0; e < NEXP; ++e) {
      float v = acc[e];
      for (int o = 32; o > 0; o >>= 1) v += __shfl_xor(v, o);
      lg[e] = v + rb[e];
    }
    int i0 = 0; float m0 = lg[0];
#pragma unroll
    for (int e = 1; e < NEXP; ++e) if (lg[e] > m0) { m0 = lg[e]; i0 = e; }
    int i1 = -1; float m1 = -3.4e38f;
#pragma unroll
    for (int e = 0; e < NEXP; ++e) if (e != i0 && lg[e] > m1) { m1 = lg[e]; i1 = e; }
    float g0 = 1.f / (1.f + expf(m1 - m0));
    float g1 = 1.f - g0;
    if (lane == 0) {
      tok_e[2 * t] = i0; tok_e[2 * t + 1] = i1;
      tok_g[2 * t] = g0; tok_g[2 * t + 1] = g1;
      atomicAdd(&hist[i0], 1); atomicAdd(&hist[i1], 1);  // LDS atomics
    }
  }
  // fused x -> bf16 for this block's 16 rows (L1/L2-hot)
  {
    const float* xs = x + (size_t)blockIdx.x * 16 * DIM;
    ushort* xd = xb + (size_t)blockIdx.x * 16 * DIM;
    for (int i = threadIdx.x; i < 16 * DIM / 4; i += 256) {
      float4 v = *(const float4*)(xs + i * 4);
      ushort4 u = { f2bf(v.x), f2bf(v.y), f2bf(v.z), f2bf(v.w) };
      *(ushort4*)(xd + i * 4) = u;
    }
  }
  __syncthreads();
  if (threadIdx.x < NEXP) blkcnt[blockIdx.x * NEXP + threadIdx.x] = hist[threadIdx.x];
}

// ---------------- scan: blkcnt[1024][8] -> offs[9], blkbase[1024][8] (parallel) ----------
__global__ __launch_bounds__(512) void scan_kernel(const int* __restrict__ blkcnt,
                                                   int* __restrict__ blkbase,
                                                   int* __restrict__ offs) {
  __shared__ int s[64][8];
  __shared__ int chunkoff[64][8];
  __shared__ int offsh[8];
  int tid = threadIdx.x;
  int e = tid & 7, chunk = tid >> 3;   // 64 chunks x 16 blocks
  int b0 = chunk * 16;
  int csum = 0;
#pragma unroll
  for (int b = 0; b < 16; ++b) csum += blkcnt[(b0 + b) * 8 + e];
  s[chunk][e] = csum;
  __syncthreads();
  int wave = tid >> 6, lane = tid & 63;
  int v = s[lane][wave];
  for (int o = 1; o < 64; o <<= 1) {
    int u = __shfl_up(v, o);
    if (lane >= o) v += u;
  }
  if (lane == 63) offsh[wave] = v;
  chunkoff[lane][wave] = v - s[lane][wave];
  __syncthreads();
  if (tid < 9) {
    int oe = 0;
    for (int j = 0; j < tid && j < 8; ++j) oe += offsh[j];
    offs[tid] = oe;
  }
  int oe2 = 0;
#pragma unroll
  for (int j = 0; j < 8; ++j) oe2 += (j < e) ? offsh[j] : 0;
  int base = oe2 + chunkoff[chunk][e];
  for (int b = 0; b < 16; ++b) {
    int idx = (b0 + b) * 8 + e;
    int c = blkcnt[idx];
    blkbase[idx] = base;
    base += c;
  }
}

// ---------------- gather: slot lists; slot_token packs token | k<<16 ----------------
__global__ __launch_bounds__(64) void gather_kernel(
    const int* __restrict__ tok_e, const float* __restrict__ tok_g,
    const int* __restrict__ blkbase, int* __restrict__ slot_token,
    float* __restrict__ slot_gate) {
  __shared__ int lcnt[NEXP];
  int tid = threadIdx.x, blk = blockIdx.x;   // 1024 blocks x 16 tokens
  if (tid < NEXP) lcnt[tid] = blkbase[blk * NEXP + tid];
  __syncthreads();
  if (tid < 32) {
    int t = blk * 16 + (tid >> 1);
    int k = tid & 1;
    int e = tok_e[2 * t + k];
    int s = atomicAdd(&lcnt[e], 1);   // LDS atomic
    slot_token[s] = t | (k << 16);
    slot_gate[s] = tok_g[2 * t + k];
  }
}

// ---------------- transpose + f32->bf16 convert (vectorized: float4 loads, 16B stores) ----
// src: [E][R][C] f32  ->  dst: [E][C][R] bf16
template <int R, int C>
__global__ __launch_bounds__(256) void transpose_cvt(const float* __restrict__ src,
                                                     ushort* __restrict__ dst) {
  __shared__ float tile[64][65];
  int e = blockIdx.z;
  const float* s = src + (size_t)e * R * C;
  ushort* d = dst + (size_t)e * R * C;
  int r0 = blockIdx.y * 64, c0 = blockIdx.x * 64;
  int tid = threadIdx.x;
#pragma unroll
  for (int i = 0; i < 4; ++i) {
    int idx = i * 256 + tid;            // 0..1023 -> 64 rows x 16 float4
    int r = idx >> 4, c4 = (idx & 15) * 4;
    float4 v = *(const float4*)(s + (size_t)(r0 + r) * C + c0 + c4);
    tile[r][c4] = v.x; tile[r][c4 + 1] = v.y; tile[r][c4 + 2] = v.z; tile[r][c4 + 3] = v.w;
  }
  __syncthreads();
#pragma unroll
  for (int i = 0; i < 2; ++i) {
    int idx = i * 256 + tid;            // 0..511 -> 64 out-rows x 8 groups of 8
    int orow = idx >> 3, g = (idx & 7) * 8;
    uint32_t p0 = (uint32_t)f2bf(tile[g + 0][orow]) | ((uint32_t)f2bf(tile[g + 1][orow]) << 16);
    uint32_t p1 = (uint32_t)f2bf(tile[g + 2][orow]) | ((uint32_t)f2bf(tile[g + 3][orow]) << 16);
    uint32_t p2 = (uint32_t)f2bf(tile[g + 4][orow]) | ((uint32_t)f2bf(tile[g + 5][orow]) << 16);
    uint32_t p3 = (uint32_t)f2bf(tile[g + 6][orow]) | ((uint32_t)f2bf(tile[g + 7][orow]) << 16);
    int4 v = { (int)p0, (int)p1, (int)p2, (int)p3 };
    *(int4*)(d + (size_t)(c0 + orow) * R + r0 + g) = v;
  }
}

// ====== 256x256 grouped GEMM, 8 waves, BK=32, 4-buf depth-3 counted-vmcnt (round-11 core) ==
// (setprio removed: regression confirmed round 12 — lockstep barriers give no role split)

// gemm1: h = relu(x_gather @ w1T^T + b1)   K=1024 -> T=32 subtiles
__global__ __launch_bounds__(512, 1) void gemm1_kernel(
    const ushort* __restrict__ xb, const ushort* __restrict__ w1T,
    const float* __restrict__ b1, const int* __restrict__ offs,
    const int* __restrict__ slot_token, ushort* __restrict__ h) {
  int flat = blockIdx.x;                     // nwg = 8*64*8 = 4096
  int swz = (flat & 7) * 512 + (flat >> 3);  // XCD x -> expert x
  int e = swz >> 9;
  int rem = swz & 511;
  int mt = rem >> 3;
  int nt = rem & 7;
  int off = offs[e];
  int cn = offs[e + 1] - off;
  if (mt * 256 >= cn) return;

  __shared__ __align__(16) ushort AB[4 * 16384];  // 128 KB
  __shared__ int toks[256];
  int tid = threadIdx.x;
  if (tid < 256) {
    int r = mt * 256 + tid;
    toks[tid] = slot_token[off + (r < cn ? r : 0)] & 0xffff;
  }
  __syncthreads();
  int wave = tid >> 6, lane = tid & 63;
  int wm = (wave >> 2) * 128, wn = (wave & 3) * 64;

  const ushort* Bsrc = w1T + (size_t)e * HID * DIM + (size_t)(nt * 256) * DIM;
  int colsw = ((lane & 3) ^ ((lane >> 3) & 3)) * 8;  // pre-swizzled source col (elems)
  int r0 = wave * 16 + (lane >> 2);
  const ushort* ag0 = xb + (size_t)toks[r0] * DIM + colsw;
  const ushort* ag1 = xb + (size_t)toks[128 + r0] * DIM + colsw;
  const ushort* bg0 = Bsrc + (size_t)r0 * DIM + colsw;
  const ushort* bg1 = Bsrc + (size_t)(128 + r0) * DIM + colsw;
  int ldsA0 = (wave * 16) * BK;
  int ldsA1 = (128 + wave * 16) * BK;
  int ldsB0 = 8192 + ldsA0;
  int ldsB1 = 8192 + ldsA1;

  f32x4 acc[8][4];
#pragma unroll
  for (int i = 0; i < 8; ++i)
#pragma unroll
    for (int j = 0; j < 4; ++j) acc[i][j] = (f32x4){0.f, 0.f, 0.f, 0.f};

  int rdo = (lane & 15) * 64 + ((((lane >> 4) & 3) << 4) ^ ((((lane & 15) >> 1) & 3) << 4));

  auto stage = [&](int buf) {
    ushort* lb = &AB[buf * 16384];
    gload_lds16(ag0, lb + ldsA0); ag0 += BK;
    gload_lds16(ag1, lb + ldsA1); ag1 += BK;
    gload_lds16(bg0, lb + ldsB0); bg0 += BK;
    gload_lds16(bg1, lb + ldsB1); bg1 += BK;
  };
  auto compute = [&](int buf) {
    const char* base = (const char*)AB + (size_t)buf * 32768;
    bf16x8 a[8], b[4];
#pragma unroll
    for (int mi = 0; mi < 8; ++mi)
      a[mi] = *(const bf16x8*)(base + (wm + mi * 16) * 64 + rdo);
#pragma unroll
    for (int ni = 0; ni < 4; ++ni)
      b[ni] = *(const bf16x8*)(base + 16384 + (wn + ni * 16) * 64 + rdo);
#pragma unroll
    for (int mi = 0; mi < 8; ++mi)
#pragma unroll
      for (int ni = 0; ni < 4; ++ni)
        acc[mi][ni] = __builtin_amdgcn_mfma_f32_16x16x32_bf16(a[mi], b[ni], acc[mi][ni], 0, 0, 0);
  };

  const int T = DIM / BK;  // 32
  stage(0); stage(1); stage(2);
  for (int t4 = 0; t4 < T - 4; t4 += 4) {
    WAITV(8); PBAR(); stage(3); compute(0);
    WAITV(8); PBAR(); stage(0); compute(1);
    WAITV(8); PBAR(); stage(1); compute(2);
    WAITV(8); PBAR(); stage(2); compute(3);
  }
  WAITV(8); PBAR(); stage(3); compute(0);
  WAITV(8); PBAR(); compute(1);
  WAITV(4); PBAR(); compute(2);
  WAITV(0); PBAR(); compute(3);

  // ---- epilogue: bias+relu -> bf16 -> swizzled LDS C[256][512B] (aliases AB) ----
  __syncthreads();
  char* Cb = (char*)AB;
  int ln = lane & 15, lg4 = (lane >> 4) * 4;
#pragma unroll
  for (int ni = 0; ni < 4; ++ni) {
    int coll = wn + ni * 16 + ln;               // local col 0..255
    float bias = b1[(size_t)e * HID + nt * 256 + coll];
#pragma unroll
    for (int mi = 0; mi < 8; ++mi) {
#pragma unroll
      for (int rg = 0; rg < 4; ++rg) {
        int row = wm + mi * 16 + lg4 + rg;      // local row 0..255
        float v = fmaxf(acc[mi][ni][rg] + bias, 0.f);
        int slot = (coll >> 3) ^ (row & 7);
        *(ushort*)(Cb + row * 512 + slot * 16 + (coll & 7) * 2) = f2bf(v);
      }
    }
  }
  __syncthreads();
#pragma unroll
  for (int rr = 0; rr < 16; ++rr) {
    int row = rr * 16 + (tid >> 5);
    int scol = tid & 31;
    int4 v = *(const int4*)(Cb + row * 512 + ((scol ^ (row & 7)) << 4));
    int r = mt * 256 + row;
    if (r < cn)
      *(int4*)(h + (size_t)(off + r) * HID + nt * 256 + scol * 8) = v;
  }
}

// gemm2: y[2t+k] = gate * (h @ w2T^T + b2)  (bf16, non-atomic scatter; y aliases d_out)
__global__ __launch_bounds__(512, 1) void gemm2_kernel(
    const ushort* __restrict__ h, const ushort* __restrict__ w2T,
    const float* __restrict__ b2, const int* __restrict__ offs,
    const int* __restrict__ slot_token, const float* __restrict__ slot_gate,
    ushort* __restrict__ y) {
  int flat = blockIdx.x;                     // nwg = 4*64*8 = 2048
  int swz = (flat & 7) * 256 + (flat >> 3);  // XCD x -> expert x
  int e = swz >> 8;
  int rem = swz & 255;
  int mt = rem >> 2;
  int nt = rem & 3;
  int off = offs[e];
  int cn = offs[e + 1] - off;
  if (mt * 256 >= cn) return;

  __shared__ __align__(16) ushort AB[4 * 16384];  // 128 KB
  __shared__ int yrows[256];
  __shared__ float gts[256];
  int tid = threadIdx.x;
  if (tid < 256) {
    int r = mt * 256 + tid;
    int s = off + (r < cn ? r : 0);
    int tk = slot_token[s];
    yrows[tid] = ((tk & 0xffff) << 1) | (tk >> 16);
    gts[tid] = slot_gate[s];
  }
  __syncthreads();
  int wave = tid >> 6, lane = tid & 63;
  int wm = (wave >> 2) * 128, wn = (wave & 3) * 64;

  const ushort* Bsrc = w2T + (size_t)e * DIM * HID + (size_t)(nt * 256) * HID;
  int colsw = ((lane & 3) ^ ((lane >> 3) & 3)) * 8;
  int r0 = wave * 16 + (lane >> 2);
  int ra0 = mt * 256 + r0;       ra0 = ra0 < cn ? ra0 : 0;
  int ra1 = mt * 256 + 128 + r0; ra1 = ra1 < cn ? ra1 : 0;
  const ushort* ag0 = h + (size_t)(off + ra0) * HID + colsw;
  const ushort* ag1 = h + (size_t)(off + ra1) * HID + colsw;
  const ushort* bg0 = Bsrc + (size_t)r0 * HID + colsw;
  const ushort* bg1 = Bsrc + (size_t)(128 + r0) * HID + colsw;
  int ldsA0 = (wave * 16) * BK;
  int ldsA1 = (128 + wave * 16) * BK;
  int ldsB0 = 8192 + ldsA0;
  int ldsB1 = 8192 + ldsA1;

  f32x4 acc[8][4];
#pragma unroll
  for (int i = 0; i < 8; ++i)
#pragma unroll
    for (int j = 0; j < 4; ++j) acc[i][j] = (f32x4){0.f, 0.f, 0.f, 0.f};

  int rdo = (lane & 15) * 64 + ((((lane >> 4) & 3) << 4) ^ ((((lane & 15) >> 1) & 3) << 4));

  auto stage = [&](int buf) {
    ushort* lb = &AB[buf * 16384];
    gload_lds16(ag0, lb + ldsA0); ag0 += BK;
    gload_lds16(ag1, lb + ldsA1); ag1 += BK;
    gload_lds16(bg0, lb + ldsB0); bg0 += BK;
    gload_lds16(bg1, lb + ldsB1); bg1 += BK;
  };
  auto compute = [&](int buf) {
    const char* base = (const char*)AB + (size_t)buf * 32768;
    bf16x8 a[8], b[4];
#pragma unroll
    for (int mi = 0; mi < 8; ++mi)
      a[mi] = *(const bf16x8*)(base + (wm + mi * 16) * 64 + rdo);
#pragma unroll
    for (int ni = 0; ni < 4; ++ni)
      b[ni] = *(const bf16x8*)(base + 16384 + (wn + ni * 16) * 64 + rdo);
#pragma unroll
    for (int mi = 0; mi < 8; ++mi)
#pragma unroll
      for (int ni = 0; ni < 4; ++ni)
        acc[mi][ni] = __builtin_amdgcn_mfma_f32_16x16x32_bf16(a[mi], b[ni], acc[mi][ni], 0, 0, 0);
  };

  const int T = HID / BK;  // 64
  stage(0); stage(1); stage(2);
  for (int t4 = 0; t4 < T - 4; t4 += 4) {
    WAITV(8); PBAR(); stage(3); compute(0);
    WAITV(8); PBAR(); stage(0); compute(1);
    WAITV(8); PBAR(); stage(1); compute(2);
    WAITV(8); PBAR(); stage(2); compute(3);
  }
  WAITV(8); PBAR(); stage(3); compute(0);
  WAITV(8); PBAR(); compute(1);
  WAITV(4); PBAR(); compute(2);
  WAITV(0); PBAR(); compute(3);

  // ---- epilogue: gate*(acc+bias) -> bf16 -> swizzled LDS C (aliases AB) -> 16B stores ----
  __syncthreads();
  char* Cb = (char*)AB;
  int ln = lane & 15, lg4 = (lane >> 4) * 4;
#pragma unroll
  for (int ni = 0; ni < 4; ++ni) {
    int coll = wn + ni * 16 + ln;
    float bias = b2[(size_t)e * DIM + nt * 256 + coll];
#pragma unroll
    for (int mi = 0; mi < 8; ++mi) {
#pragma unroll
      for (int rg = 0; rg < 4; ++rg) {
        int row = wm + mi * 16 + lg4 + rg;
        float v = gts[row] * (acc[mi][ni][rg] + bias);
        int slot = (coll >> 3) ^ (row & 7);
        *(ushort*)(Cb + row * 512 + slot * 16 + (coll & 7) * 2) = f2bf(v);
      }
    }
  }
  __syncthreads();
#pragma unroll
  for (int rr = 0; rr < 16; ++rr) {
    int row = rr * 16 + (tid >> 5);
    int scol = tid & 31;
    int4 v = *(const int4*)(Cb + row * 512 + ((scol ^ (row & 7)) << 4));
    int r = mt * 256 + row;
    if (r < cn)
      *(int4*)(y + (size_t)yrows[row] * DIM + nt * 256 + scol * 8) = v;
  }
}

// ---------------- combine: out[t] = y[2t] + y[2t+1] (in-place, y aliases out) ------------
__global__ __launch_bounds__(256) void combine_kernel(float* __restrict__ out) {
  int t = blockIdx.x;
  int d = threadIdx.x;  // 4 outputs each
  const ushort* y = (const ushort*)out;
  ushort4 a = *(const ushort4*)(y + (size_t)(2 * t) * DIM + 4 * d);
  ushort4 b = *(const ushort4*)(y + (size_t)(2 * t + 1) * DIM + 4 * d);
  float4 r;
  r.x = bf2f(a.x) + bf2f(b.x);
  r.y = bf2f(a.y) + bf2f(b.y);
  r.z = bf2f(a.z) + bf2f(b.z);
  r.w = bf2f(a.w) + bf2f(b.w);
  __syncthreads();  // all loads of this block's 4KB before any store over it
  *(float4*)(out + (size_t)t * DIM + 4 * d) = r;
}

extern "C" void kernel_launch(void* const* d_in, const int* in_sizes, int n_in,
                              void* d_out, int out_size, void* d_ws, size_t ws_size,
                              hipStream_t stream) {
  const float* x  = (const float*)d_in[0];
  const float* rw = (const float*)d_in[1];
  const float* rb = (const float*)d_in[2];
  const float* w1 = (const float*)d_in[3];
  const float* b1 = (const float*)d_in[4];
  const float* w2 = (const float*)d_in[5];
  const float* b2 = (const float*)d_in[6];
  float* out = (float*)d_out;
  char* ws = (char*)d_ws;

  const size_t o_ctrl = 0;                    // offs[9] (+pad)
  const size_t o_toke = 256;
  const size_t o_tokg = o_toke + 131072;
  const size_t o_stok = o_tokg + 131072;
  const size_t o_sgat = o_stok + 131072;
  const size_t o_xb   = o_sgat + 131072;
  const size_t o_w1T  = o_xb + (size_t)N_TOK * DIM * 2;
  const size_t o_h    = o_w1T + (size_t)NEXP * HID * DIM * 2;
  const size_t required = o_h + (size_t)N_TOK * 2 * HID * 2;  // ~202 MB
  if (ws_size < required) {
    fprintf(stderr, "kernel_launch: ws too small: have %zu need %zu\n", ws_size, required);
    return;
  }
  int* offs       = (int*)(ws + o_ctrl);
  int* tok_e      = (int*)(ws + o_toke);
  float* tok_g    = (float*)(ws + o_tokg);
  int* slot_token = (int*)(ws + o_stok);
  float* slot_gate= (float*)(ws + o_sgat);
  ushort* xb      = (ushort*)(ws + o_xb);
  ushort* w2T     = (ushort*)(ws + o_xb);   // aliased with xb (xb dead after gemm1)
  ushort* w1T     = (ushort*)(ws + o_w1T);
  ushort* hbuf    = (ushort*)(ws + o_h);
  int* blkcnt     = (int*)(ws + o_h);       // aliases hbuf (pre-gemm1 only)
  int* blkbase    = blkcnt + 1024 * NEXP;

  // no memsets needed: router/scan/gather write all control words; gemm2's slot map is a
  // bijection onto all y rows and nt covers all columns, so every d_out byte is written.

  // router (+fused x->bf16) -> scan -> gather
  router_kernel<<<N_TOK / 16, 256, 0, stream>>>(x, rw, rb, blkcnt, tok_e, tok_g, xb);
  scan_kernel<<<1, 512, 0, stream>>>(blkcnt, blkbase, offs);
  gather_kernel<<<N_TOK / 16, 64, 0, stream>>>(tok_e, tok_g, blkbase, slot_token, slot_gate);

  // w1 [E][D][H] -> w1T [E][H][D]
  transpose_cvt<DIM, HID><<<dim3(HID / 64, DIM / 64, NEXP), 256, 0, stream>>>(w1, w1T);

  gemm1_kernel<<<8 * 64 * NEXP, 512, 0, stream>>>(xb, w1T, b1, offs, slot_token, hbuf);

  // xb dead; build w2T in its place: w2 [E][H][D] -> w2T [E][D][H]
  transpose_cvt<HID, DIM><<<dim3(DIM / 64, HID / 64, NEXP), 256, 0, stream>>>(w2, w2T);

  // gemm2 scatters gated bf16 rows into y (aliases d_out), then combine in-place
  gemm2_kernel<<<4 * 64 * NEXP, 512, 0, stream>>>(hbuf, w2T, b2, offs, slot_token, slot_gate,
                                                  (ushort*)d_out);
  combine_kernel<<<N_TOK, 256, 0, stream>>>(out);
}